// Round 6
// baseline (716.584 us; speedup 1.0000x reference)
//
#include <hip/hip_runtime.h>

// ---------------------------------------------------------------------------
// ModulatedConvBlock on MI355X (gfx950) — round 6
// Conv = bf16 MFMA implicit GEMM. 512-thr blocks (8 waves), 2 blocks/CU
// = 16 waves/CU for latency hiding. Weights in registers, prefetched
// 2 phases ahead from L2-resident packed buffer. LDS holds xm only
// (double-buffered across cc, swizzle key (row>>1)&3). One barrier per cc
// with counted vmcnt(8) (fresh weight prefetches stay in flight).
// ---------------------------------------------------------------------------

typedef short bf16x8 __attribute__((ext_vector_type(8)));
typedef short short8v __attribute__((ext_vector_type(8)));
typedef float f32x16 __attribute__((ext_vector_type(16)));

// workspace layout (bytes)
#define WS_STYLE 0            // [8][512] f32
#define WS_DEMOD 16384        // [8][512] f32
#define WS_WSQ   32768        // [512][512] f32
#define WS_WPACK 1081344      // [tap9][cc16][o512][kg4][8] bf16 (4718592 B)
#define WS_XM    5799936      // [8][66][66][512] bf16 (35684352 B)

__device__ __forceinline__ short f2bf(float f) {
  unsigned u = __float_as_uint(f);
  u += 0x7FFFu + ((u >> 16) & 1u);   // round-to-nearest-even
  return (short)(u >> 16);
}

__device__ __forceinline__ void gld16(const short* g, char* l) {
  __builtin_amdgcn_global_load_lds((const __attribute__((address_space(1))) void*)g,
                                   (__attribute__((address_space(3))) void*)l,
                                   16, 0, 0);
}

// ---------------- style_std[b][i] = (sb[b]*0.0625) @ aw[i] + ab[i] + 1 ------
__global__ void k_style(const float* __restrict__ sb, const float* __restrict__ aw,
                        const float* __restrict__ ab, float* __restrict__ style) {
  __shared__ float s_sb[512];
  int b = blockIdx.x;
  for (int i = threadIdx.x; i < 512; i += 256) s_sb[i] = sb[b * 512 + i] * 0.0625f;
  __syncthreads();
  for (int i = threadIdx.x; i < 512; i += 256) {
    const float4* wrow = (const float4*)(aw + (size_t)i * 512);
    float acc = 0.f;
    #pragma unroll 4
    for (int s4 = 0; s4 < 128; ++s4) {
      float4 w4 = wrow[s4];
      float4 sv = *(const float4*)(s_sb + s4 * 4);
      acc += w4.x * sv.x + w4.y * sv.y + w4.z * sv.z + w4.w * sv.w;
    }
    style[b * 512 + i] = acc + ab[i] + 1.0f;
  }
}

// ---------------- wsq[o][i] = sum_tap conv_w^2 ------------------------------
__global__ void k_wsq(const float* __restrict__ cw, float* __restrict__ wsq) {
  int idx = blockIdx.x * 256 + threadIdx.x;   // o*512+i
  const float* p = cw + (size_t)idx * 9;
  float s = 0.f;
  #pragma unroll
  for (int j = 0; j < 9; ++j) s += p[j] * p[j];
  wsq[idx] = s;
}

// ---------------- demod[b][o] = rsqrt(sum_i wsq[o][i]*style^2 + eps) --------
__global__ void k_demod(const float* __restrict__ wsq, const float* __restrict__ style,
                        float* __restrict__ demod) {
  int wid = threadIdx.x >> 6, lane = threadIdx.x & 63;
  int idx = blockIdx.x * 4 + wid;             // (b,o)
  int b = idx >> 9, o = idx & 511;
  const float* wr = wsq + (size_t)o * 512;
  const float* ss = style + b * 512;
  float sum = 0.f;
  #pragma unroll
  for (int k = 0; k < 8; ++k) {
    int i = k * 64 + lane;
    float s = ss[i];
    sum += wr[i] * s * s;
  }
  #pragma unroll
  for (int off = 32; off; off >>= 1) sum += __shfl_down(sum, off);
  if (lane == 0) demod[b * 512 + o] = rsqrtf(sum + 1e-8f);
}

// ---------------- upsample 2x bilinear (half-pixel) + modulate, NHWC pad ----
__global__ void k_upsample(const float* __restrict__ x, const float* __restrict__ style,
                           short* __restrict__ xm) {
  int b = blockIdx.x / 66, hp = blockIdx.x % 66;
  short* xmp = xm + ((size_t)b * 66 + hp) * 66 * 512;
  if (hp == 0 || hp == 65) {
    short8v z = {0, 0, 0, 0, 0, 0, 0, 0};
    for (int u = threadIdx.x; u < 66 * 512 / 8; u += 256) ((short8v*)xmp)[u] = z;
    return;
  }
  int h = hp - 1;
  int j0 = (h >> 1) - 1 + (h & 1);
  float fj = (h & 1) ? 0.25f : 0.75f;
  int j0c = j0 < 0 ? 0 : j0;
  int j1c = j0 + 1 > 31 ? 31 : j0 + 1;
  __shared__ float xt[2][64][33];
  int ccc = threadIdx.x & 63;
  int wsub = threadIdx.x >> 6;
  for (int c0 = 0; c0 < 512; c0 += 64) {
    __syncthreads();
    #pragma unroll 4
    for (int k = 0; k < 16; ++k) {
      int idx = k * 256 + threadIdx.x;
      int ii = idx & 31, cc = (idx >> 5) & 63, jj = idx >> 11;
      xt[jj][cc][ii] = x[(((size_t)b * 512 + c0 + cc) * 32 + (jj ? j1c : j0c)) * 32 + ii];
    }
    __syncthreads();
    float sstyle = style[b * 512 + c0 + ccc];
    #pragma unroll 4
    for (int wk = 0; wk < 16; ++wk) {
      int w = wk * 4 + wsub;
      int i0 = (w >> 1) - 1 + (w & 1);
      float fi = (w & 1) ? 0.25f : 0.75f;
      int i0c = i0 < 0 ? 0 : i0;
      int i1c = i0 + 1 > 31 ? 31 : i0 + 1;
      float v0 = xt[0][ccc][i0c] * (1.f - fi) + xt[0][ccc][i1c] * fi;
      float v1 = xt[1][ccc][i0c] * (1.f - fi) + xt[1][ccc][i1c] * fi;
      float v = (v0 * (1.f - fj) + v1 * fj) * sstyle;
      xmp[(size_t)(w + 1) * 512 + c0 + ccc] = f2bf(v);
    }
    if (wsub == 0) {
      xmp[c0 + ccc] = 0;
      xmp[(size_t)65 * 512 + c0 + ccc] = 0;
    }
  }
}

// ---------------- weight pack (consumed into registers) ---------------------
// wpk[tap][cc][o][kg][j] = w[o][ cc*32 + kg*8 + j ][tap]
__global__ void k_packw(const float* __restrict__ cw, short* __restrict__ wpk) {
  int unit = blockIdx.x * 256 + threadIdx.x;  // < 294912
  int s = unit >> 11;                          // tap*16+cc
  int rem = unit & 2047;
  int o = rem >> 2, kg = rem & 3;
  int tap = s >> 4, cc = s & 15;
  int i0 = cc * 32 + (kg << 3);
  const float* src = cw + ((size_t)o * 512 + i0) * 9 + tap;
  short8v v;
  #pragma unroll
  for (int j = 0; j < 8; ++j) v[j] = f2bf(src[j * 9]);
  *(short8v*)(wpk + (size_t)unit * 8) = v;
}

// ---------------- main conv: 2 blocks/CU, 8 waves each, reg weights ---------
// grid 512 = 2nt x 32hpair x 8b ; block 512 thr
// wave (wo in {0..3}, wsrow in {0,1}): 64 cout x row(hpair*2+wsrow) x 64 w
__global__ __launch_bounds__(512, 4) void k_conv(
    const short* __restrict__ xm, const short* __restrict__ wpk,
    const float* __restrict__ demod, const float* __restrict__ convb,
    const float* __restrict__ nscal, const float* __restrict__ noise,
    const float* __restrict__ t, const float* __restrict__ prelu_a,
    float* __restrict__ y) {
  __shared__ char XMs[2][16896];   // [4 r][66 wp][4 slot]x16B per buffer

  int tid = threadIdx.x;
  int bid = blockIdx.x;
  int nt = bid & 1, hpair = (bid >> 1) & 31, b = bid >> 6;
  int wid = tid >> 6, lane = tid & 63;
  int wo = wid & 3, wsrow = wid >> 2;
  int l31 = lane & 31, lg = lane >> 5;

  const short* xb = xm + ((size_t)b * 66 + hpair * 2) * 66 * 512;
  // per-lane weight base (shorts); fragment (cf,hf) at + cf*1024 + hf*16;
  // slab (tap,cc) at + (tap*16+cc)*16384
  const short* wlp = wpk + (size_t)((nt * 256 + wo * 64 + l31) * 32 + lg * 8);

  // ---- prologue: stage XM (cc=0, 1056 units over 512 threads) ----
  {
    int u = tid;
    int r = u / 264, rem = u - r * 264;
    int wp = rem >> 2, spp = rem & 3;
    gld16(xb + (size_t)(r * 66 + wp) * 512 + ((spp ^ ((wp >> 1) & 3)) << 3), XMs[0] + u * 16);
    u = 512 + tid;
    r = u / 264; rem = u - r * 264;
    wp = rem >> 2; spp = rem & 3;
    gld16(xb + (size_t)(r * 66 + wp) * 512 + ((spp ^ ((wp >> 1) & 3)) << 3), XMs[0] + u * 16);
    if (tid < 32) {
      u = 1024 + tid;
      rem = u - 792;               // r = 3
      wp = rem >> 2; spp = rem & 3;
      gld16(xb + (size_t)(3 * 66 + wp) * 512 + ((spp ^ ((wp >> 1) & 3)) << 3), XMs[0] + u * 16);
    }
  }

  // prologue weights: wc = slab(tap0,cc0), wn1 = slab(tap1,cc0)
  bf16x8 wcA = *(const bf16x8*)(wlp + 0);
  bf16x8 wcC = *(const bf16x8*)(wlp + 16);
  bf16x8 wcB = *(const bf16x8*)(wlp + 1024);
  bf16x8 wcD = *(const bf16x8*)(wlp + 1040);
  const short* w1p = wlp + 16 * 16384;
  bf16x8 w1A = *(const bf16x8*)(w1p + 0);
  bf16x8 w1C = *(const bf16x8*)(w1p + 16);
  bf16x8 w1B = *(const bf16x8*)(w1p + 1024);
  bf16x8 w1D = *(const bf16x8*)(w1p + 1040);

  f32x16 zf = {0,0,0,0,0,0,0,0,0,0,0,0,0,0,0,0};
  f32x16 acc[2][2];
  acc[0][0] = zf; acc[0][1] = zf; acc[1][0] = zf; acc[1][1] = zf;

  asm volatile("s_waitcnt vmcnt(0) lgkmcnt(0)" ::: "memory");
  __builtin_amdgcn_s_barrier();
  __builtin_amdgcn_sched_barrier(0);

  #pragma unroll 1
  for (int cc = 0; cc < 16; ++cc) {
    const char* XMc = XMs[cc & 1];
    char* XMn = XMs[(cc & 1) ^ 1];
    #pragma unroll
    for (int tap = 0; tap < 9; ++tap) {
      const int kh = tap / 3, kw = tap % 3;

      // 1. prefetch weights for phase+2 into wn2 (registers)
      bf16x8 w2A, w2B, w2C, w2D;
      {
        int ntap = (tap <= 6) ? (tap + 2) : (tap - 7);
        int ncc  = (tap <= 6) ? cc : (cc + 1);
        if (ncc > 15) ncc = 15;
        const short* wsrc = wlp + (size_t)(ntap * 16 + ncc) * 16384;
        w2A = *(const bf16x8*)(wsrc + 0);
        w2C = *(const bf16x8*)(wsrc + 16);
        w2B = *(const bf16x8*)(wsrc + 1024);
        w2D = *(const bf16x8*)(wsrc + 1040);
      }
      // 2. next-cc xm staging, taps 0..2 (1056 units over 512 threads)
      if (cc < 15) {
        if (tap == 0) {
          int u = tid;
          int r = u / 264, rem = u - r * 264;
          int wp = rem >> 2, spp = rem & 3;
          gld16(xb + (size_t)(r * 66 + wp) * 512 + (cc + 1) * 32 + ((spp ^ ((wp >> 1) & 3)) << 3),
                XMn + u * 16);
        } else if (tap == 1) {
          int u = 512 + tid;
          int r = u / 264, rem = u - r * 264;
          int wp = rem >> 2, spp = rem & 3;
          gld16(xb + (size_t)(r * 66 + wp) * 512 + (cc + 1) * 32 + ((spp ^ ((wp >> 1) & 3)) << 3),
                XMn + u * 16);
        } else if (tap == 2 && tid < 32) {
          int u = 1024 + tid;
          int rem = u - 792;         // r = 3
          int wp = rem >> 2, spp = rem & 3;
          gld16(xb + (size_t)(3 * 66 + wp) * 512 + (cc + 1) * 32 + ((spp ^ ((wp >> 1) & 3)) << 3),
                XMn + u * 16);
        }
      }

      // 3. compute: 4 ds_read_b128 + 8 MFMA
      int a = l31 + kw;
      int xo = ((wsrow + kh) * 66 + a) * 64 + ((lg ^ ((a >> 1) & 3)) << 4);
      bf16x8 xf00 = *(const bf16x8*)(XMc + xo);           // sf0, hf0
      bf16x8 xf01 = *(const bf16x8*)(XMc + xo + 2048);    // sf1, hf0
      bf16x8 xf10 = *(const bf16x8*)(XMc + (xo ^ 32));    // sf0, hf1
      bf16x8 xf11 = *(const bf16x8*)(XMc + ((xo ^ 32) + 2048));

      __builtin_amdgcn_s_setprio(1);
      acc[0][0] = __builtin_amdgcn_mfma_f32_32x32x16_bf16(wcA, xf00, acc[0][0], 0, 0, 0);
      acc[0][1] = __builtin_amdgcn_mfma_f32_32x32x16_bf16(wcA, xf01, acc[0][1], 0, 0, 0);
      acc[1][0] = __builtin_amdgcn_mfma_f32_32x32x16_bf16(wcB, xf00, acc[1][0], 0, 0, 0);
      acc[1][1] = __builtin_amdgcn_mfma_f32_32x32x16_bf16(wcB, xf01, acc[1][1], 0, 0, 0);
      acc[0][0] = __builtin_amdgcn_mfma_f32_32x32x16_bf16(wcC, xf10, acc[0][0], 0, 0, 0);
      acc[0][1] = __builtin_amdgcn_mfma_f32_32x32x16_bf16(wcC, xf11, acc[0][1], 0, 0, 0);
      acc[1][0] = __builtin_amdgcn_mfma_f32_32x32x16_bf16(wcD, xf10, acc[1][0], 0, 0, 0);
      acc[1][1] = __builtin_amdgcn_mfma_f32_32x32x16_bf16(wcD, xf11, acc[1][1], 0, 0, 0);
      __builtin_amdgcn_s_setprio(0);

      // 4. rotate prefetch pipeline (renamed by the unrolled tap loop)
      wcA = w1A; wcB = w1B; wcC = w1C; wcD = w1D;
      w1A = w2A; w1B = w2B; w1C = w2C; w1D = w2D;

      // 5. cc-boundary sync: xm buffer swap. vmcnt(8) keeps the 8 newest
      // loads (tap7+tap8 weight prefetches) in flight; all gld16 staging
      // (taps 0..2, >=6 phases old) is drained.
      if (tap == 8) {
        __builtin_amdgcn_sched_barrier(0);
        asm volatile("s_waitcnt vmcnt(8) lgkmcnt(0)" ::: "memory");
        __builtin_amdgcn_s_barrier();
        __builtin_amdgcn_sched_barrier(0);
      }
    }
  }

  // ---- epilogue: demod + bias + noise + prelu + (y+t)/sqrt2 ----
  float pa = prelu_a[0];
  const float inv_r2 = 1.0f / 1.41421f;
  int h = hpair * 2 + wsrow;
  float nz0 = noise[((size_t)b * 64 + h) * 64 + l31];
  float nz1 = noise[((size_t)b * 64 + h) * 64 + 32 + l31];
  #pragma unroll
  for (int cf = 0; cf < 2; ++cf) {
    #pragma unroll
    for (int reg = 0; reg < 16; ++reg) {
      int orow = (reg & 3) + 8 * (reg >> 2) + 4 * lg;
      int o = nt * 256 + wo * 64 + cf * 32 + orow;
      float dm = demod[b * 512 + o];
      float cb = convb[o];
      float ns = nscal[o];
      #pragma unroll
      for (int sf = 0; sf < 2; ++sf) {
        int w = sf * 32 + l31;
        float v = acc[cf][sf][reg];
        v = v * dm + cb + ns * (sf ? nz1 : nz0);
        v = (v >= 0.f) ? v : pa * v;
        size_t oi = (((size_t)b * 512 + o) * 64 + h) * 64 + w;
        v = (v + t[oi]) * inv_r2;
        y[oi] = v;
      }
    }
  }
}

// ---------------- toRGB: 1x1 conv over 512 ch + clamp -----------------------
__global__ void k_rgb(const float* __restrict__ y, const float* __restrict__ ow,
                      const float* __restrict__ ob, float* __restrict__ out) {
  int b = blockIdx.x >> 6, h = blockIdx.x & 63;
  int w = threadIdx.x & 63, g = threadIdx.x >> 6;
  const float* yb = y + (((size_t)b * 512) * 64 + h) * 64 + w;
  float s0 = 0.f, s1 = 0.f, s2 = 0.f;
  for (int o = g * 128; o < g * 128 + 128; ++o) {
    float v = yb[(size_t)o * 4096];
    s0 += v * ow[o];
    s1 += v * ow[512 + o];
    s2 += v * ow[1024 + o];
  }
  __shared__ float red[3][4][64];
  red[0][g][w] = s0; red[1][g][w] = s1; red[2][g][w] = s2;
  __syncthreads();
  if (threadIdx.x < 192) {
    int c = threadIdx.x >> 6, ww = threadIdx.x & 63;
    float s = red[c][0][ww] + red[c][1][ww] + red[c][2][ww] + red[c][3][ww];
    s = s * 0.0625f + ob[c];
    s = fminf(fmaxf(s, 0.f), 1.f);
    out[(((size_t)b * 3 + c) * 64 + h) * 64 + ww] = s;
  }
}

extern "C" void kernel_launch(void* const* d_in, const int* in_sizes, int n_in,
                              void* d_out, int out_size, void* d_ws, size_t ws_size,
                              hipStream_t stream) {
  const float* x     = (const float*)d_in[0];
  const float* sb    = (const float*)d_in[1];
  const float* noise = (const float*)d_in[2];
  const float* t     = (const float*)d_in[3];
  const float* aw    = (const float*)d_in[4];
  const float* ab    = (const float*)d_in[5];
  const float* cw    = (const float*)d_in[6];
  const float* cb    = (const float*)d_in[7];
  const float* pa    = (const float*)d_in[8];
  const float* ns    = (const float*)d_in[9];
  const float* ow    = (const float*)d_in[10];
  const float* ob    = (const float*)d_in[11];
  char* ws = (char*)d_ws;
  float* style = (float*)(ws + WS_STYLE);
  float* demod = (float*)(ws + WS_DEMOD);
  float* wsq   = (float*)(ws + WS_WSQ);
  short* wpk   = (short*)(ws + WS_WPACK);
  short* xm    = (short*)(ws + WS_XM);
  float* y   = (float*)d_out;
  float* out = y + 16777216;

  k_style<<<8, 256, 0, stream>>>(sb, aw, ab, style);
  k_wsq<<<1024, 256, 0, stream>>>(cw, wsq);
  k_demod<<<1024, 256, 0, stream>>>(wsq, style, demod);
  k_upsample<<<528, 256, 0, stream>>>(x, style, xm);
  k_packw<<<1152, 256, 0, stream>>>(cw, wpk);
  k_conv<<<512, 512, 0, stream>>>(xm, wpk, demod, cb, ns, noise, t, pa, y);
  k_rgb<<<512, 256, 0, stream>>>(y, ow, ob, out);
}

// Round 7
// 281.484 us; speedup vs baseline: 2.5457x; 2.5457x over previous
//
#include <hip/hip_runtime.h>

// ---------------------------------------------------------------------------
// ModulatedConvBlock on MI355X (gfx950) — round 7
// Conv = bf16 MFMA implicit GEMM. 256-thr blocks (4 waves), grid 1024
// = 4 blocks/CU = 16 waves/CU (4/SIMD) for latency hiding.
// Register budget: acc 64 AGPR + ~52 VGPR < 128 total (launch_bounds(256,4)).
// Weights read in-phase from L2-resident packed buffer (no prefetch regs);
// TLP hides the vmcnt stall. LDS holds xm only (dbuf across cc, swizzle
// key (row>>1)&3). Barriers only at cc boundaries.
// ---------------------------------------------------------------------------

typedef short bf16x8 __attribute__((ext_vector_type(8)));
typedef short short8v __attribute__((ext_vector_type(8)));
typedef float f32x16 __attribute__((ext_vector_type(16)));

// workspace layout (bytes)
#define WS_STYLE 0            // [8][512] f32
#define WS_DEMOD 16384        // [8][512] f32
#define WS_WSQ   32768        // [512][512] f32
#define WS_WPACK 1081344      // [tap9][cc16][o512][kg4][8] bf16 (4718592 B)
#define WS_XM    5799936      // [8][66][66][512] bf16 (35684352 B)

__device__ __forceinline__ short f2bf(float f) {
  unsigned u = __float_as_uint(f);
  u += 0x7FFFu + ((u >> 16) & 1u);   // round-to-nearest-even
  return (short)(u >> 16);
}

__device__ __forceinline__ void gld16(const short* g, char* l) {
  __builtin_amdgcn_global_load_lds((const __attribute__((address_space(1))) void*)g,
                                   (__attribute__((address_space(3))) void*)l,
                                   16, 0, 0);
}

// ---------------- style_std[b][i] = (sb[b]*0.0625) @ aw[i] + ab[i] + 1 ------
__global__ void k_style(const float* __restrict__ sb, const float* __restrict__ aw,
                        const float* __restrict__ ab, float* __restrict__ style) {
  __shared__ float s_sb[512];
  int b = blockIdx.x;
  for (int i = threadIdx.x; i < 512; i += 256) s_sb[i] = sb[b * 512 + i] * 0.0625f;
  __syncthreads();
  for (int i = threadIdx.x; i < 512; i += 256) {
    const float4* wrow = (const float4*)(aw + (size_t)i * 512);
    float acc = 0.f;
    #pragma unroll 4
    for (int s4 = 0; s4 < 128; ++s4) {
      float4 w4 = wrow[s4];
      float4 sv = *(const float4*)(s_sb + s4 * 4);
      acc += w4.x * sv.x + w4.y * sv.y + w4.z * sv.z + w4.w * sv.w;
    }
    style[b * 512 + i] = acc + ab[i] + 1.0f;
  }
}

// ---------------- wsq[o][i] = sum_tap conv_w^2 ------------------------------
__global__ void k_wsq(const float* __restrict__ cw, float* __restrict__ wsq) {
  int idx = blockIdx.x * 256 + threadIdx.x;   // o*512+i
  const float* p = cw + (size_t)idx * 9;
  float s = 0.f;
  #pragma unroll
  for (int j = 0; j < 9; ++j) s += p[j] * p[j];
  wsq[idx] = s;
}

// ---------------- demod[b][o] = rsqrt(sum_i wsq[o][i]*style^2 + eps) --------
__global__ void k_demod(const float* __restrict__ wsq, const float* __restrict__ style,
                        float* __restrict__ demod) {
  int wid = threadIdx.x >> 6, lane = threadIdx.x & 63;
  int idx = blockIdx.x * 4 + wid;             // (b,o)
  int b = idx >> 9, o = idx & 511;
  const float* wr = wsq + (size_t)o * 512;
  const float* ss = style + b * 512;
  float sum = 0.f;
  #pragma unroll
  for (int k = 0; k < 8; ++k) {
    int i = k * 64 + lane;
    float s = ss[i];
    sum += wr[i] * s * s;
  }
  #pragma unroll
  for (int off = 32; off; off >>= 1) sum += __shfl_down(sum, off);
  if (lane == 0) demod[b * 512 + o] = rsqrtf(sum + 1e-8f);
}

// ---------------- upsample 2x bilinear (half-pixel) + modulate, NHWC pad ----
__global__ void k_upsample(const float* __restrict__ x, const float* __restrict__ style,
                           short* __restrict__ xm) {
  int b = blockIdx.x / 66, hp = blockIdx.x % 66;
  short* xmp = xm + ((size_t)b * 66 + hp) * 66 * 512;
  if (hp == 0 || hp == 65) {
    short8v z = {0, 0, 0, 0, 0, 0, 0, 0};
    for (int u = threadIdx.x; u < 66 * 512 / 8; u += 256) ((short8v*)xmp)[u] = z;
    return;
  }
  int h = hp - 1;
  int j0 = (h >> 1) - 1 + (h & 1);
  float fj = (h & 1) ? 0.25f : 0.75f;
  int j0c = j0 < 0 ? 0 : j0;
  int j1c = j0 + 1 > 31 ? 31 : j0 + 1;
  __shared__ float xt[2][64][33];
  int ccc = threadIdx.x & 63;
  int wsub = threadIdx.x >> 6;
  for (int c0 = 0; c0 < 512; c0 += 64) {
    __syncthreads();
    #pragma unroll 4
    for (int k = 0; k < 16; ++k) {
      int idx = k * 256 + threadIdx.x;
      int ii = idx & 31, cc = (idx >> 5) & 63, jj = idx >> 11;
      xt[jj][cc][ii] = x[(((size_t)b * 512 + c0 + cc) * 32 + (jj ? j1c : j0c)) * 32 + ii];
    }
    __syncthreads();
    float sstyle = style[b * 512 + c0 + ccc];
    #pragma unroll 4
    for (int wk = 0; wk < 16; ++wk) {
      int w = wk * 4 + wsub;
      int i0 = (w >> 1) - 1 + (w & 1);
      float fi = (w & 1) ? 0.25f : 0.75f;
      int i0c = i0 < 0 ? 0 : i0;
      int i1c = i0 + 1 > 31 ? 31 : i0 + 1;
      float v0 = xt[0][ccc][i0c] * (1.f - fi) + xt[0][ccc][i1c] * fi;
      float v1 = xt[1][ccc][i0c] * (1.f - fi) + xt[1][ccc][i1c] * fi;
      float v = (v0 * (1.f - fj) + v1 * fj) * sstyle;
      xmp[(size_t)(w + 1) * 512 + c0 + ccc] = f2bf(v);
    }
    if (wsub == 0) {
      xmp[c0 + ccc] = 0;
      xmp[(size_t)65 * 512 + c0 + ccc] = 0;
    }
  }
}

// ---------------- weight pack (consumed into registers) ---------------------
// wpk[tap][cc][o][kg][j] = w[o][ cc*32 + kg*8 + j ][tap]
__global__ void k_packw(const float* __restrict__ cw, short* __restrict__ wpk) {
  int unit = blockIdx.x * 256 + threadIdx.x;  // < 294912
  int s = unit >> 11;                          // tap*16+cc
  int rem = unit & 2047;
  int o = rem >> 2, kg = rem & 3;
  int tap = s >> 4, cc = s & 15;
  int i0 = cc * 32 + (kg << 3);
  const float* src = cw + ((size_t)o * 512 + i0) * 9 + tap;
  short8v v;
  #pragma unroll
  for (int j = 0; j < 8; ++j) v[j] = f2bf(src[j * 9]);
  *(short8v*)(wpk + (size_t)unit * 8) = v;
}

// ---------------- main conv: 4 blocks/CU, 4 waves each, reg weights ---------
// grid 1024 = 4nt x 32hpair x 8b ; block 256 thr
// wave (wo in {0,1}, wsrow in {0,1}): 64 cout x row(hpair*2+wsrow) x 64 w
__global__ __launch_bounds__(256, 4) void k_conv(
    const short* __restrict__ xm, const short* __restrict__ wpk,
    const float* __restrict__ demod, const float* __restrict__ convb,
    const float* __restrict__ nscal, const float* __restrict__ noise,
    const float* __restrict__ t, const float* __restrict__ prelu_a,
    float* __restrict__ y) {
  __shared__ char XMs[2][16896];   // [4 r][66 wp][4 slot]x16B per buffer

  int tid = threadIdx.x;
  int bid = blockIdx.x;
  int nt = bid & 3, hpair = (bid >> 2) & 31, b = bid >> 7;
  int wid = tid >> 6, lane = tid & 63;
  int wo = wid & 1, wsrow = wid >> 1;
  int l31 = lane & 31, lg = lane >> 5;

  const short* xb = xm + ((size_t)b * 66 + hpair * 2) * 66 * 512;
  // per-lane weight base (shorts) inside a (tap,cc) slab of 16384 shorts;
  // frag offsets: A(cf0,kg=lg)=0, C(cf0,kg=2+lg)=16, B(cf1)=+1024, D=+1040
  const short* wlp = wpk + (size_t)((nt * 128 + wo * 64 + l31) * 32 + lg * 8);

  // ---- prologue: stage XM (cc=0, 1056 units over 256 threads) ----
  #pragma unroll
  for (int k = 0; k < 4; ++k) {
    int u = k * 256 + tid;
    int r = u / 264, rem = u - r * 264;
    int wp = rem >> 2, spp = rem & 3;
    gld16(xb + (size_t)(r * 66 + wp) * 512 + ((spp ^ ((wp >> 1) & 3)) << 3), XMs[0] + u * 16);
  }
  if (tid < 32) {
    int u = 1024 + tid;
    int rem = u - 792;              // r = 3
    int wp = rem >> 2, spp = rem & 3;
    gld16(xb + (size_t)(3 * 66 + wp) * 512 + ((spp ^ ((wp >> 1) & 3)) << 3), XMs[0] + u * 16);
  }

  f32x16 zf = {0,0,0,0,0,0,0,0,0,0,0,0,0,0,0,0};
  f32x16 acc[2][2];
  acc[0][0] = zf; acc[0][1] = zf; acc[1][0] = zf; acc[1][1] = zf;

  asm volatile("s_waitcnt vmcnt(0) lgkmcnt(0)" ::: "memory");
  __builtin_amdgcn_s_barrier();
  __builtin_amdgcn_sched_barrier(0);

  #pragma unroll 1
  for (int cc = 0; cc < 16; ++cc) {
    const char* XMc = XMs[cc & 1];
    char* XMn = XMs[(cc & 1) ^ 1];
    #pragma unroll
    for (int tap = 0; tap < 9; ++tap) {
      const int kh = tap / 3, kw = tap % 3;

      // 1. weight loads for THIS phase (L2-resident; TLP hides the wait)
      const short* wsrc = wlp + (size_t)(tap * 16 + cc) * 16384;
      bf16x8 wcA = *(const bf16x8*)(wsrc + 0);
      bf16x8 wcC = *(const bf16x8*)(wsrc + 16);
      bf16x8 wcB = *(const bf16x8*)(wsrc + 1024);
      bf16x8 wcD = *(const bf16x8*)(wsrc + 1040);

      // 2. next-cc xm staging, spread over taps 0..4
      if (cc < 15) {
        if (tap < 4) {
          int u = tap * 256 + tid;
          int r = u / 264, rem = u - r * 264;
          int wp = rem >> 2, spp = rem & 3;
          gld16(xb + (size_t)(r * 66 + wp) * 512 + (cc + 1) * 32 + ((spp ^ ((wp >> 1) & 3)) << 3),
                XMn + u * 16);
        } else if (tap == 4 && tid < 32) {
          int u = 1024 + tid;
          int rem = u - 792;         // r = 3
          int wp = rem >> 2, spp = rem & 3;
          gld16(xb + (size_t)(3 * 66 + wp) * 512 + (cc + 1) * 32 + ((spp ^ ((wp >> 1) & 3)) << 3),
                XMn + u * 16);
        }
      }

      // 3. compute: 4 ds_read_b128 + 8 MFMA
      int a = l31 + kw;
      int xo = ((wsrow + kh) * 66 + a) * 64 + ((lg ^ ((a >> 1) & 3)) << 4);
      bf16x8 xf00 = *(const bf16x8*)(XMc + xo);           // w 0-31,  kg lg
      bf16x8 xf01 = *(const bf16x8*)(XMc + xo + 2048);    // w 32-63, kg lg
      bf16x8 xf10 = *(const bf16x8*)(XMc + (xo ^ 32));    // w 0-31,  kg 2+lg
      bf16x8 xf11 = *(const bf16x8*)(XMc + ((xo ^ 32) + 2048));

      __builtin_amdgcn_s_setprio(1);
      acc[0][0] = __builtin_amdgcn_mfma_f32_32x32x16_bf16(wcA, xf00, acc[0][0], 0, 0, 0);
      acc[0][1] = __builtin_amdgcn_mfma_f32_32x32x16_bf16(wcA, xf01, acc[0][1], 0, 0, 0);
      acc[1][0] = __builtin_amdgcn_mfma_f32_32x32x16_bf16(wcB, xf00, acc[1][0], 0, 0, 0);
      acc[1][1] = __builtin_amdgcn_mfma_f32_32x32x16_bf16(wcB, xf01, acc[1][1], 0, 0, 0);
      acc[0][0] = __builtin_amdgcn_mfma_f32_32x32x16_bf16(wcC, xf10, acc[0][0], 0, 0, 0);
      acc[0][1] = __builtin_amdgcn_mfma_f32_32x32x16_bf16(wcC, xf11, acc[0][1], 0, 0, 0);
      acc[1][0] = __builtin_amdgcn_mfma_f32_32x32x16_bf16(wcD, xf10, acc[1][0], 0, 0, 0);
      acc[1][1] = __builtin_amdgcn_mfma_f32_32x32x16_bf16(wcD, xf11, acc[1][1], 0, 0, 0);
      __builtin_amdgcn_s_setprio(0);

      // 4. cc-boundary sync: xm buffer swap (all outstanding loads aged)
      if (tap == 8) {
        __builtin_amdgcn_sched_barrier(0);
        asm volatile("s_waitcnt vmcnt(0) lgkmcnt(0)" ::: "memory");
        __builtin_amdgcn_s_barrier();
        __builtin_amdgcn_sched_barrier(0);
      }
    }
  }

  // ---- epilogue: demod + bias + noise + prelu + (y+t)/sqrt2 ----
  float pa = prelu_a[0];
  const float inv_r2 = 1.0f / 1.41421f;
  int h = hpair * 2 + wsrow;
  float nz0 = noise[((size_t)b * 64 + h) * 64 + l31];
  float nz1 = noise[((size_t)b * 64 + h) * 64 + 32 + l31];
  #pragma unroll
  for (int cf = 0; cf < 2; ++cf) {
    #pragma unroll
    for (int reg = 0; reg < 16; ++reg) {
      int orow = (reg & 3) + 8 * (reg >> 2) + 4 * lg;
      int o = nt * 128 + wo * 64 + cf * 32 + orow;
      float dm = demod[b * 512 + o];
      float cb = convb[o];
      float ns = nscal[o];
      #pragma unroll
      for (int sf = 0; sf < 2; ++sf) {
        int w = sf * 32 + l31;
        float v = acc[cf][sf][reg];
        v = v * dm + cb + ns * (sf ? nz1 : nz0);
        v = (v >= 0.f) ? v : pa * v;
        size_t oi = (((size_t)b * 512 + o) * 64 + h) * 64 + w;
        v = (v + t[oi]) * inv_r2;
        y[oi] = v;
      }
    }
  }
}

// ---------------- toRGB: 1x1 conv over 512 ch + clamp -----------------------
__global__ void k_rgb(const float* __restrict__ y, const float* __restrict__ ow,
                      const float* __restrict__ ob, float* __restrict__ out) {
  int b = blockIdx.x >> 6, h = blockIdx.x & 63;
  int w = threadIdx.x & 63, g = threadIdx.x >> 6;
  const float* yb = y + (((size_t)b * 512) * 64 + h) * 64 + w;
  float s0 = 0.f, s1 = 0.f, s2 = 0.f;
  for (int o = g * 128; o < g * 128 + 128; ++o) {
    float v = yb[(size_t)o * 4096];
    s0 += v * ow[o];
    s1 += v * ow[512 + o];
    s2 += v * ow[1024 + o];
  }
  __shared__ float red[3][4][64];
  red[0][g][w] = s0; red[1][g][w] = s1; red[2][g][w] = s2;
  __syncthreads();
  if (threadIdx.x < 192) {
    int c = threadIdx.x >> 6, ww = threadIdx.x & 63;
    float s = red[c][0][ww] + red[c][1][ww] + red[c][2][ww] + red[c][3][ww];
    s = s * 0.0625f + ob[c];
    s = fminf(fmaxf(s, 0.f), 1.f);
    out[(((size_t)b * 3 + c) * 64 + h) * 64 + ww] = s;
  }
}

extern "C" void kernel_launch(void* const* d_in, const int* in_sizes, int n_in,
                              void* d_out, int out_size, void* d_ws, size_t ws_size,
                              hipStream_t stream) {
  const float* x     = (const float*)d_in[0];
  const float* sb    = (const float*)d_in[1];
  const float* noise = (const float*)d_in[2];
  const float* t     = (const float*)d_in[3];
  const float* aw    = (const float*)d_in[4];
  const float* ab    = (const float*)d_in[5];
  const float* cw    = (const float*)d_in[6];
  const float* cb    = (const float*)d_in[7];
  const float* pa    = (const float*)d_in[8];
  const float* ns    = (const float*)d_in[9];
  const float* ow    = (const float*)d_in[10];
  const float* ob    = (const float*)d_in[11];
  char* ws = (char*)d_ws;
  float* style = (float*)(ws + WS_STYLE);
  float* demod = (float*)(ws + WS_DEMOD);
  float* wsq   = (float*)(ws + WS_WSQ);
  short* wpk   = (short*)(ws + WS_WPACK);
  short* xm    = (short*)(ws + WS_XM);
  float* y   = (float*)d_out;
  float* out = y + 16777216;

  k_style<<<8, 256, 0, stream>>>(sb, aw, ab, style);
  k_wsq<<<1024, 256, 0, stream>>>(cw, wsq);
  k_demod<<<1024, 256, 0, stream>>>(wsq, style, demod);
  k_upsample<<<528, 256, 0, stream>>>(x, style, xm);
  k_packw<<<1152, 256, 0, stream>>>(cw, wpk);
  k_conv<<<1024, 256, 0, stream>>>(xm, wpk, demod, cb, ns, noise, t, pa, y);
  k_rgb<<<512, 256, 0, stream>>>(y, ow, ob, out);
}

// Round 8
// 265.838 us; speedup vs baseline: 2.6956x; 1.0589x over previous
//
#include <hip/hip_runtime.h>

// ---------------------------------------------------------------------------
// ModulatedConvBlock on MI355X (gfx950) — round 8
// Conv = bf16 MFMA implicit GEMM. Grid 1024 (4nt x 32hpair x 8b), 256-thr
// blocks (4 waves), wave = 64 cout x 64 sp, acc[2][2] = 64 AGPR.
// R8: 3-tap mega-phases (48 phases, 24 MFMA/wave/phase) — amortize the
// per-phase latency chain 3x. Weight loads grouped at phase start (before
// staging, so counted vmcnt for MFMAs never drains fresh staging).
// __syncthreads() only at cc boundaries. No setprio/asm barriers.
// ---------------------------------------------------------------------------

typedef short bf16x8 __attribute__((ext_vector_type(8)));
typedef short short8v __attribute__((ext_vector_type(8)));
typedef float f32x16 __attribute__((ext_vector_type(16)));

// workspace layout (bytes)
#define WS_STYLE 0            // [8][512] f32
#define WS_DEMOD 16384        // [8][512] f32
#define WS_WSQ   32768        // [512][512] f32
#define WS_WPACK 1081344      // [tap9][cc16][o512][kg4][8] bf16 (4718592 B)
#define WS_XM    5799936      // [8][66][66][512] bf16 (35684352 B)

__device__ __forceinline__ short f2bf(float f) {
  unsigned u = __float_as_uint(f);
  u += 0x7FFFu + ((u >> 16) & 1u);   // round-to-nearest-even
  return (short)(u >> 16);
}

__device__ __forceinline__ void gld16(const short* g, char* l) {
  __builtin_amdgcn_global_load_lds((const __attribute__((address_space(1))) void*)g,
                                   (__attribute__((address_space(3))) void*)l,
                                   16, 0, 0);
}

// ---------------- style_std[b][i] = (sb[b]*0.0625) @ aw[i] + ab[i] + 1 ------
__global__ void k_style(const float* __restrict__ sb, const float* __restrict__ aw,
                        const float* __restrict__ ab, float* __restrict__ style) {
  __shared__ float s_sb[512];
  int b = blockIdx.x;
  for (int i = threadIdx.x; i < 512; i += 256) s_sb[i] = sb[b * 512 + i] * 0.0625f;
  __syncthreads();
  for (int i = threadIdx.x; i < 512; i += 256) {
    const float4* wrow = (const float4*)(aw + (size_t)i * 512);
    float acc = 0.f;
    #pragma unroll 4
    for (int s4 = 0; s4 < 128; ++s4) {
      float4 w4 = wrow[s4];
      float4 sv = *(const float4*)(s_sb + s4 * 4);
      acc += w4.x * sv.x + w4.y * sv.y + w4.z * sv.z + w4.w * sv.w;
    }
    style[b * 512 + i] = acc + ab[i] + 1.0f;
  }
}

// ---------------- wsq[o][i] = sum_tap conv_w^2 ------------------------------
__global__ void k_wsq(const float* __restrict__ cw, float* __restrict__ wsq) {
  int idx = blockIdx.x * 256 + threadIdx.x;   // o*512+i
  const float* p = cw + (size_t)idx * 9;
  float s = 0.f;
  #pragma unroll
  for (int j = 0; j < 9; ++j) s += p[j] * p[j];
  wsq[idx] = s;
}

// ---------------- demod[b][o] = rsqrt(sum_i wsq[o][i]*style^2 + eps) --------
__global__ void k_demod(const float* __restrict__ wsq, const float* __restrict__ style,
                        float* __restrict__ demod) {
  int wid = threadIdx.x >> 6, lane = threadIdx.x & 63;
  int idx = blockIdx.x * 4 + wid;             // (b,o)
  int b = idx >> 9, o = idx & 511;
  const float* wr = wsq + (size_t)o * 512;
  const float* ss = style + b * 512;
  float sum = 0.f;
  #pragma unroll
  for (int k = 0; k < 8; ++k) {
    int i = k * 64 + lane;
    float s = ss[i];
    sum += wr[i] * s * s;
  }
  #pragma unroll
  for (int off = 32; off; off >>= 1) sum += __shfl_down(sum, off);
  if (lane == 0) demod[b * 512 + o] = rsqrtf(sum + 1e-8f);
}

// ---------------- upsample 2x bilinear (half-pixel) + modulate, NHWC pad ----
__global__ void k_upsample(const float* __restrict__ x, const float* __restrict__ style,
                           short* __restrict__ xm) {
  int b = blockIdx.x / 66, hp = blockIdx.x % 66;
  short* xmp = xm + ((size_t)b * 66 + hp) * 66 * 512;
  if (hp == 0 || hp == 65) {
    short8v z = {0, 0, 0, 0, 0, 0, 0, 0};
    for (int u = threadIdx.x; u < 66 * 512 / 8; u += 256) ((short8v*)xmp)[u] = z;
    return;
  }
  int h = hp - 1;
  int j0 = (h >> 1) - 1 + (h & 1);
  float fj = (h & 1) ? 0.25f : 0.75f;
  int j0c = j0 < 0 ? 0 : j0;
  int j1c = j0 + 1 > 31 ? 31 : j0 + 1;
  __shared__ float xt[2][64][33];
  int ccc = threadIdx.x & 63;
  int wsub = threadIdx.x >> 6;
  for (int c0 = 0; c0 < 512; c0 += 64) {
    __syncthreads();
    #pragma unroll 4
    for (int k = 0; k < 16; ++k) {
      int idx = k * 256 + threadIdx.x;
      int ii = idx & 31, cc = (idx >> 5) & 63, jj = idx >> 11;
      xt[jj][cc][ii] = x[(((size_t)b * 512 + c0 + cc) * 32 + (jj ? j1c : j0c)) * 32 + ii];
    }
    __syncthreads();
    float sstyle = style[b * 512 + c0 + ccc];
    #pragma unroll 4
    for (int wk = 0; wk < 16; ++wk) {
      int w = wk * 4 + wsub;
      int i0 = (w >> 1) - 1 + (w & 1);
      float fi = (w & 1) ? 0.25f : 0.75f;
      int i0c = i0 < 0 ? 0 : i0;
      int i1c = i0 + 1 > 31 ? 31 : i0 + 1;
      float v0 = xt[0][ccc][i0c] * (1.f - fi) + xt[0][ccc][i1c] * fi;
      float v1 = xt[1][ccc][i0c] * (1.f - fi) + xt[1][ccc][i1c] * fi;
      float v = (v0 * (1.f - fj) + v1 * fj) * sstyle;
      xmp[(size_t)(w + 1) * 512 + c0 + ccc] = f2bf(v);
    }
    if (wsub == 0) {
      xmp[c0 + ccc] = 0;
      xmp[(size_t)65 * 512 + c0 + ccc] = 0;
    }
  }
}

// ---------------- weight pack (consumed into registers) ---------------------
// wpk[tap][cc][o][kg][j] = w[o][ cc*32 + kg*8 + j ][tap]
__global__ void k_packw(const float* __restrict__ cw, short* __restrict__ wpk) {
  int unit = blockIdx.x * 256 + threadIdx.x;  // < 294912
  int s = unit >> 11;                          // tap*16+cc
  int rem = unit & 2047;
  int o = rem >> 2, kg = rem & 3;
  int tap = s >> 4, cc = s & 15;
  int i0 = cc * 32 + (kg << 3);
  const float* src = cw + ((size_t)o * 512 + i0) * 9 + tap;
  short8v v;
  #pragma unroll
  for (int j = 0; j < 8; ++j) v[j] = f2bf(src[j * 9]);
  *(short8v*)(wpk + (size_t)unit * 8) = v;
}

// ---------------- main conv: 4-wave blocks, 3-tap mega-phases ---------------
// grid 1024 = 4nt x 32hpair x 8b ; block 256 thr
// wave (wo in {0,1}, wsrow in {0,1}): 64 cout x row(hpair*2+wsrow) x 64 w
__global__ __launch_bounds__(256, 3) void k_conv(
    const short* __restrict__ xm, const short* __restrict__ wpk,
    const float* __restrict__ demod, const float* __restrict__ convb,
    const float* __restrict__ nscal, const float* __restrict__ noise,
    const float* __restrict__ t, const float* __restrict__ prelu_a,
    float* __restrict__ y) {
  __shared__ char XMs[2][16896];   // [4 r][66 wp][4 slot]x16B per buffer

  int tid = threadIdx.x;
  int bid = blockIdx.x;
  int nt = bid & 3, hpair = (bid >> 2) & 31, b = bid >> 7;
  int wid = tid >> 6, lane = tid & 63;
  int wo = wid & 1, wsrow = wid >> 1;
  int l31 = lane & 31, lg = lane >> 5;

  const short* xb = xm + ((size_t)b * 66 + hpair * 2) * 66 * 512;
  // per-lane weight base (shorts) inside a (tap,cc) slab of 16384 shorts
  const short* wlp = wpk + (size_t)((nt * 128 + wo * 64 + l31) * 32 + lg * 8);

  // ---- prologue: stage XM (cc=0, 1056 units over 256 threads) ----
  #pragma unroll
  for (int k = 0; k < 4; ++k) {
    int u = k * 256 + tid;
    int r = u / 264, rem = u - r * 264;
    int wp = rem >> 2, spp = rem & 3;
    gld16(xb + (size_t)(r * 66 + wp) * 512 + ((spp ^ ((wp >> 1) & 3)) << 3), XMs[0] + u * 16);
  }
  if (tid < 32) {
    int u = 1024 + tid;
    int rem = u - 792;              // r = 3
    int wp = rem >> 2, spp = rem & 3;
    gld16(xb + (size_t)(3 * 66 + wp) * 512 + ((spp ^ ((wp >> 1) & 3)) << 3), XMs[0] + u * 16);
  }

  f32x16 zf = {0,0,0,0,0,0,0,0,0,0,0,0,0,0,0,0};
  f32x16 acc[2][2];
  acc[0][0] = zf; acc[0][1] = zf; acc[1][0] = zf; acc[1][1] = zf;

  __syncthreads();

  #pragma unroll 1
  for (int cc = 0; cc < 16; ++cc) {
    const char* XMc = XMs[cc & 1];
    char* XMn = XMs[(cc & 1) ^ 1];
    #pragma unroll
    for (int krow = 0; krow < 3; ++krow) {
      // --- 12 weight loads for the 3 taps of this kh row, issued FIRST ---
      const short* ws0 = wlp + (size_t)((3 * krow + 0) * 16 + cc) * 16384;
      const short* ws1 = wlp + (size_t)((3 * krow + 1) * 16 + cc) * 16384;
      const short* ws2 = wlp + (size_t)((3 * krow + 2) * 16 + cc) * 16384;
      bf16x8 wA0 = *(const bf16x8*)(ws0 + 0);
      bf16x8 wC0 = *(const bf16x8*)(ws0 + 16);
      bf16x8 wB0 = *(const bf16x8*)(ws0 + 1024);
      bf16x8 wD0 = *(const bf16x8*)(ws0 + 1040);
      bf16x8 wA1 = *(const bf16x8*)(ws1 + 0);
      bf16x8 wC1 = *(const bf16x8*)(ws1 + 16);
      bf16x8 wB1 = *(const bf16x8*)(ws1 + 1024);
      bf16x8 wD1 = *(const bf16x8*)(ws1 + 1040);
      bf16x8 wA2 = *(const bf16x8*)(ws2 + 0);
      bf16x8 wC2 = *(const bf16x8*)(ws2 + 16);
      bf16x8 wB2 = *(const bf16x8*)(ws2 + 1024);
      bf16x8 wD2 = *(const bf16x8*)(ws2 + 1040);

      // --- next-cc xm staging, issued AFTER this phase's weight loads ---
      if (cc < 15) {
        if (krow == 0) {
          #pragma unroll
          for (int k = 0; k < 2; ++k) {
            int u = k * 256 + tid;
            int r = u / 264, rem = u - r * 264;
            int wp = rem >> 2, spp = rem & 3;
            gld16(xb + (size_t)(r * 66 + wp) * 512 + (cc + 1) * 32 + ((spp ^ ((wp >> 1) & 3)) << 3),
                  XMn + u * 16);
          }
        } else if (krow == 1) {
          #pragma unroll
          for (int k = 2; k < 4; ++k) {
            int u = k * 256 + tid;
            int r = u / 264, rem = u - r * 264;
            int wp = rem >> 2, spp = rem & 3;
            gld16(xb + (size_t)(r * 66 + wp) * 512 + (cc + 1) * 32 + ((spp ^ ((wp >> 1) & 3)) << 3),
                  XMn + u * 16);
          }
          if (tid < 32) {
            int u = 1024 + tid;
            int rem = u - 792;       // r = 3
            int wp = rem >> 2, spp = rem & 3;
            gld16(xb + (size_t)(3 * 66 + wp) * 512 + (cc + 1) * 32 + ((spp ^ ((wp >> 1) & 3)) << 3),
                  XMn + u * 16);
          }
        }
      }

      // --- compute: 12 ds_read_b128 + 24 MFMA (3 taps, kh = krow) ---
      int a0 = l31 + 0;
      int a1 = l31 + 1;
      int a2 = l31 + 2;
      int rbase = (wsrow + krow) * 66;
      int xo0 = (rbase + a0) * 64 + ((lg ^ ((a0 >> 1) & 3)) << 4);
      int xo1 = (rbase + a1) * 64 + ((lg ^ ((a1 >> 1) & 3)) << 4);
      int xo2 = (rbase + a2) * 64 + ((lg ^ ((a2 >> 1) & 3)) << 4);
      bf16x8 xf00 = *(const bf16x8*)(XMc + xo0);
      bf16x8 xf01 = *(const bf16x8*)(XMc + xo0 + 2048);
      bf16x8 xf02 = *(const bf16x8*)(XMc + (xo0 ^ 32));
      bf16x8 xf03 = *(const bf16x8*)(XMc + ((xo0 ^ 32) + 2048));
      bf16x8 xf10 = *(const bf16x8*)(XMc + xo1);
      bf16x8 xf11 = *(const bf16x8*)(XMc + xo1 + 2048);
      bf16x8 xf12 = *(const bf16x8*)(XMc + (xo1 ^ 32));
      bf16x8 xf13 = *(const bf16x8*)(XMc + ((xo1 ^ 32) + 2048));
      bf16x8 xf20 = *(const bf16x8*)(XMc + xo2);
      bf16x8 xf21 = *(const bf16x8*)(XMc + xo2 + 2048);
      bf16x8 xf22 = *(const bf16x8*)(XMc + (xo2 ^ 32));
      bf16x8 xf23 = *(const bf16x8*)(XMc + ((xo2 ^ 32) + 2048));

      acc[0][0] = __builtin_amdgcn_mfma_f32_32x32x16_bf16(wA0, xf00, acc[0][0], 0, 0, 0);
      acc[0][1] = __builtin_amdgcn_mfma_f32_32x32x16_bf16(wA0, xf01, acc[0][1], 0, 0, 0);
      acc[1][0] = __builtin_amdgcn_mfma_f32_32x32x16_bf16(wB0, xf00, acc[1][0], 0, 0, 0);
      acc[1][1] = __builtin_amdgcn_mfma_f32_32x32x16_bf16(wB0, xf01, acc[1][1], 0, 0, 0);
      acc[0][0] = __builtin_amdgcn_mfma_f32_32x32x16_bf16(wC0, xf02, acc[0][0], 0, 0, 0);
      acc[0][1] = __builtin_amdgcn_mfma_f32_32x32x16_bf16(wC0, xf03, acc[0][1], 0, 0, 0);
      acc[1][0] = __builtin_amdgcn_mfma_f32_32x32x16_bf16(wD0, xf02, acc[1][0], 0, 0, 0);
      acc[1][1] = __builtin_amdgcn_mfma_f32_32x32x16_bf16(wD0, xf03, acc[1][1], 0, 0, 0);

      acc[0][0] = __builtin_amdgcn_mfma_f32_32x32x16_bf16(wA1, xf10, acc[0][0], 0, 0, 0);
      acc[0][1] = __builtin_amdgcn_mfma_f32_32x32x16_bf16(wA1, xf11, acc[0][1], 0, 0, 0);
      acc[1][0] = __builtin_amdgcn_mfma_f32_32x32x16_bf16(wB1, xf10, acc[1][0], 0, 0, 0);
      acc[1][1] = __builtin_amdgcn_mfma_f32_32x32x16_bf16(wB1, xf11, acc[1][1], 0, 0, 0);
      acc[0][0] = __builtin_amdgcn_mfma_f32_32x32x16_bf16(wC1, xf12, acc[0][0], 0, 0, 0);
      acc[0][1] = __builtin_amdgcn_mfma_f32_32x32x16_bf16(wC1, xf13, acc[0][1], 0, 0, 0);
      acc[1][0] = __builtin_amdgcn_mfma_f32_32x32x16_bf16(wD1, xf12, acc[1][0], 0, 0, 0);
      acc[1][1] = __builtin_amdgcn_mfma_f32_32x32x16_bf16(wD1, xf13, acc[1][1], 0, 0, 0);

      acc[0][0] = __builtin_amdgcn_mfma_f32_32x32x16_bf16(wA2, xf20, acc[0][0], 0, 0, 0);
      acc[0][1] = __builtin_amdgcn_mfma_f32_32x32x16_bf16(wA2, xf21, acc[0][1], 0, 0, 0);
      acc[1][0] = __builtin_amdgcn_mfma_f32_32x32x16_bf16(wB2, xf20, acc[1][0], 0, 0, 0);
      acc[1][1] = __builtin_amdgcn_mfma_f32_32x32x16_bf16(wB2, xf21, acc[1][1], 0, 0, 0);
      acc[0][0] = __builtin_amdgcn_mfma_f32_32x32x16_bf16(wC2, xf22, acc[0][0], 0, 0, 0);
      acc[0][1] = __builtin_amdgcn_mfma_f32_32x32x16_bf16(wC2, xf23, acc[0][1], 0, 0, 0);
      acc[1][0] = __builtin_amdgcn_mfma_f32_32x32x16_bf16(wD2, xf22, acc[1][0], 0, 0, 0);
      acc[1][1] = __builtin_amdgcn_mfma_f32_32x32x16_bf16(wD2, xf23, acc[1][1], 0, 0, 0);
    }
    // cc boundary: xm dbuf swap. Staging is >=1 full mega-phase old here,
    // so the implicit vmcnt(0) drain is cheap.
    __syncthreads();
  }

  // ---- epilogue: demod + bias + noise + prelu + (y+t)/sqrt2 ----
  float pa = prelu_a[0];
  const float inv_r2 = 1.0f / 1.41421f;
  int h = hpair * 2 + wsrow;
  float nz0 = noise[((size_t)b * 64 + h) * 64 + l31];
  float nz1 = noise[((size_t)b * 64 + h) * 64 + 32 + l31];
  #pragma unroll
  for (int cf = 0; cf < 2; ++cf) {
    #pragma unroll
    for (int reg = 0; reg < 16; ++reg) {
      int orow = (reg & 3) + 8 * (reg >> 2) + 4 * lg;
      int o = nt * 128 + wo * 64 + cf * 32 + orow;
      float dm = demod[b * 512 + o];
      float cb = convb[o];
      float ns = nscal[o];
      #pragma unroll
      for (int sf = 0; sf < 2; ++sf) {
        int w = sf * 32 + l31;
        float v = acc[cf][sf][reg];
        v = v * dm + cb + ns * (sf ? nz1 : nz0);
        v = (v >= 0.f) ? v : pa * v;
        size_t oi = (((size_t)b * 512 + o) * 64 + h) * 64 + w;
        v = (v + t[oi]) * inv_r2;
        y[oi] = v;
      }
    }
  }
}

// ---------------- toRGB: 1x1 conv over 512 ch + clamp -----------------------
__global__ void k_rgb(const float* __restrict__ y, const float* __restrict__ ow,
                      const float* __restrict__ ob, float* __restrict__ out) {
  int b = blockIdx.x >> 6, h = blockIdx.x & 63;
  int w = threadIdx.x & 63, g = threadIdx.x >> 6;
  const float* yb = y + (((size_t)b * 512) * 64 + h) * 64 + w;
  float s0 = 0.f, s1 = 0.f, s2 = 0.f;
  for (int o = g * 128; o < g * 128 + 128; ++o) {
    float v = yb[(size_t)o * 4096];
    s0 += v * ow[o];
    s1 += v * ow[512 + o];
    s2 += v * ow[1024 + o];
  }
  __shared__ float red[3][4][64];
  red[0][g][w] = s0; red[1][g][w] = s1; red[2][g][w] = s2;
  __syncthreads();
  if (threadIdx.x < 192) {
    int c = threadIdx.x >> 6, ww = threadIdx.x & 63;
    float s = red[c][0][ww] + red[c][1][ww] + red[c][2][ww] + red[c][3][ww];
    s = s * 0.0625f + ob[c];
    s = fminf(fmaxf(s, 0.f), 1.f);
    out[(((size_t)b * 3 + c) * 64 + h) * 64 + ww] = s;
  }
}

extern "C" void kernel_launch(void* const* d_in, const int* in_sizes, int n_in,
                              void* d_out, int out_size, void* d_ws, size_t ws_size,
                              hipStream_t stream) {
  const float* x     = (const float*)d_in[0];
  const float* sb    = (const float*)d_in[1];
  const float* noise = (const float*)d_in[2];
  const float* t     = (const float*)d_in[3];
  const float* aw    = (const float*)d_in[4];
  const float* ab    = (const float*)d_in[5];
  const float* cw    = (const float*)d_in[6];
  const float* cb    = (const float*)d_in[7];
  const float* pa    = (const float*)d_in[8];
  const float* ns    = (const float*)d_in[9];
  const float* ow    = (const float*)d_in[10];
  const float* ob    = (const float*)d_in[11];
  char* ws = (char*)d_ws;
  float* style = (float*)(ws + WS_STYLE);
  float* demod = (float*)(ws + WS_DEMOD);
  float* wsq   = (float*)(ws + WS_WSQ);
  short* wpk   = (short*)(ws + WS_WPACK);
  short* xm    = (short*)(ws + WS_XM);
  float* y   = (float*)d_out;
  float* out = y + 16777216;

  k_style<<<8, 256, 0, stream>>>(sb, aw, ab, style);
  k_wsq<<<1024, 256, 0, stream>>>(cw, wsq);
  k_demod<<<1024, 256, 0, stream>>>(wsq, style, demod);
  k_upsample<<<528, 256, 0, stream>>>(x, style, xm);
  k_packw<<<1152, 256, 0, stream>>>(cw, wpk);
  k_conv<<<1024, 256, 0, stream>>>(xm, wpk, demod, cb, ns, noise, t, pa, y);
  k_rgb<<<512, 256, 0, stream>>>(y, ow, ob, out);
}

// Round 9
// 265.002 us; speedup vs baseline: 2.7041x; 1.0032x over previous
//
#include <hip/hip_runtime.h>

// ---------------------------------------------------------------------------
// ModulatedConvBlock on MI355X (gfx950) — round 9
// Conv = bf16 MFMA implicit GEMM, full T3+T4 schedule:
//   1 block/CU (grid 256, 512 thr, 8 waves). Wave = 128 cout x 64 sp.
//   Weights: LDS ring[3] x 32KB, staged tap+2 ahead via gld16 (4/thread/phase,
//   uniform stream). xm: LDS dbuf, staged via reg-loads (tap0) + ds_write
//   (tap7) so it never pollutes the vmcnt stream. Counted vmcnt(4)/(7) at
//   phase ends — never 0 in the main loop. 2 barriers/phase + setprio.
//   Both operands XOR-bank-swizzled (key (row>>1)&3, pre-baked in pack/stage).
// ---------------------------------------------------------------------------

typedef short bf16x8 __attribute__((ext_vector_type(8)));
typedef short short8v __attribute__((ext_vector_type(8)));
typedef float f32x16 __attribute__((ext_vector_type(16)));

// workspace layout (bytes)
#define WS_STYLE 0            // [8][512] f32
#define WS_DEMOD 16384        // [8][512] f32
#define WS_WSQ   32768        // [512][512] f32
#define WS_WPACK 1081344      // [tap9][cc16][o512][sp4][8] bf16 (4718592 B)
#define WS_XM    5799936      // [8][66][66][512] bf16 (35684352 B)

__device__ __forceinline__ short f2bf(float f) {
  unsigned u = __float_as_uint(f);
  u += 0x7FFFu + ((u >> 16) & 1u);   // round-to-nearest-even
  return (short)(u >> 16);
}

__device__ __forceinline__ void gld16(const short* g, char* l) {
  __builtin_amdgcn_global_load_lds((const __attribute__((address_space(1))) void*)g,
                                   (__attribute__((address_space(3))) void*)l,
                                   16, 0, 0);
}

// ---------------- style_std[b][i] = (sb[b]*0.0625) @ aw[i] + ab[i] + 1 ------
__global__ void k_style(const float* __restrict__ sb, const float* __restrict__ aw,
                        const float* __restrict__ ab, float* __restrict__ style) {
  __shared__ float s_sb[512];
  int b = blockIdx.x;
  for (int i = threadIdx.x; i < 512; i += 256) s_sb[i] = sb[b * 512 + i] * 0.0625f;
  __syncthreads();
  for (int i = threadIdx.x; i < 512; i += 256) {
    const float4* wrow = (const float4*)(aw + (size_t)i * 512);
    float acc = 0.f;
    #pragma unroll 4
    for (int s4 = 0; s4 < 128; ++s4) {
      float4 w4 = wrow[s4];
      float4 sv = *(const float4*)(s_sb + s4 * 4);
      acc += w4.x * sv.x + w4.y * sv.y + w4.z * sv.z + w4.w * sv.w;
    }
    style[b * 512 + i] = acc + ab[i] + 1.0f;
  }
}

// ---------------- wsq[o][i] = sum_tap conv_w^2 ------------------------------
__global__ void k_wsq(const float* __restrict__ cw, float* __restrict__ wsq) {
  int idx = blockIdx.x * 256 + threadIdx.x;   // o*512+i
  const float* p = cw + (size_t)idx * 9;
  float s = 0.f;
  #pragma unroll
  for (int j = 0; j < 9; ++j) s += p[j] * p[j];
  wsq[idx] = s;
}

// ---------------- demod[b][o] = rsqrt(sum_i wsq[o][i]*style^2 + eps) --------
__global__ void k_demod(const float* __restrict__ wsq, const float* __restrict__ style,
                        float* __restrict__ demod) {
  int wid = threadIdx.x >> 6, lane = threadIdx.x & 63;
  int idx = blockIdx.x * 4 + wid;             // (b,o)
  int b = idx >> 9, o = idx & 511;
  const float* wr = wsq + (size_t)o * 512;
  const float* ss = style + b * 512;
  float sum = 0.f;
  #pragma unroll
  for (int k = 0; k < 8; ++k) {
    int i = k * 64 + lane;
    float s = ss[i];
    sum += wr[i] * s * s;
  }
  #pragma unroll
  for (int off = 32; off; off >>= 1) sum += __shfl_down(sum, off);
  if (lane == 0) demod[b * 512 + o] = rsqrtf(sum + 1e-8f);
}

// ---------------- upsample 2x bilinear (half-pixel) + modulate, NHWC pad ----
__global__ void k_upsample(const float* __restrict__ x, const float* __restrict__ style,
                           short* __restrict__ xm) {
  int b = blockIdx.x / 66, hp = blockIdx.x % 66;
  short* xmp = xm + ((size_t)b * 66 + hp) * 66 * 512;
  if (hp == 0 || hp == 65) {
    short8v z = {0, 0, 0, 0, 0, 0, 0, 0};
    for (int u = threadIdx.x; u < 66 * 512 / 8; u += 256) ((short8v*)xmp)[u] = z;
    return;
  }
  int h = hp - 1;
  int j0 = (h >> 1) - 1 + (h & 1);
  float fj = (h & 1) ? 0.25f : 0.75f;
  int j0c = j0 < 0 ? 0 : j0;
  int j1c = j0 + 1 > 31 ? 31 : j0 + 1;
  __shared__ float xt[2][64][33];
  int ccc = threadIdx.x & 63;
  int wsub = threadIdx.x >> 6;
  for (int c0 = 0; c0 < 512; c0 += 64) {
    __syncthreads();
    #pragma unroll 4
    for (int k = 0; k < 16; ++k) {
      int idx = k * 256 + threadIdx.x;
      int ii = idx & 31, cc = (idx >> 5) & 63, jj = idx >> 11;
      xt[jj][cc][ii] = x[(((size_t)b * 512 + c0 + cc) * 32 + (jj ? j1c : j0c)) * 32 + ii];
    }
    __syncthreads();
    float sstyle = style[b * 512 + c0 + ccc];
    #pragma unroll 4
    for (int wk = 0; wk < 16; ++wk) {
      int w = wk * 4 + wsub;
      int i0 = (w >> 1) - 1 + (w & 1);
      float fi = (w & 1) ? 0.25f : 0.75f;
      int i0c = i0 < 0 ? 0 : i0;
      int i1c = i0 + 1 > 31 ? 31 : i0 + 1;
      float v0 = xt[0][ccc][i0c] * (1.f - fi) + xt[0][ccc][i1c] * fi;
      float v1 = xt[1][ccc][i0c] * (1.f - fi) + xt[1][ccc][i1c] * fi;
      float v = (v0 * (1.f - fj) + v1 * fj) * sstyle;
      xmp[(size_t)(w + 1) * 512 + c0 + ccc] = f2bf(v);
    }
    if (wsub == 0) {
      xmp[c0 + ccc] = 0;
      xmp[(size_t)65 * 512 + c0 + ccc] = 0;
    }
  }
}

// ---------------- weight pack WITH bank pre-swizzle -------------------------
// wpk[tap][cc][o][sp][j] = w[o][ cc*32 + (sp ^ ((o>>1)&3))*8 + j ][tap]
__global__ void k_packw(const float* __restrict__ cw, short* __restrict__ wpk) {
  int unit = blockIdx.x * 256 + threadIdx.x;  // < 294912
  int s = unit >> 11;                          // tap*16+cc
  int rem = unit & 2047;
  int o = rem >> 2, sp = rem & 3;
  int tap = s >> 4, cc = s & 15;
  int i0 = cc * 32 + ((sp ^ ((o >> 1) & 3)) << 3);
  const float* src = cw + ((size_t)o * 512 + i0) * 9 + tap;
  short8v v;
  #pragma unroll
  for (int j = 0; j < 8; ++j) v[j] = f2bf(src[j * 9]);
  *(short8v*)(wpk + (size_t)unit * 8) = v;
}

// ---------------- main conv: 1 block/CU, 8 waves, T3+T4 schedule ------------
// grid 256 = 32hpair x 8b ; block 512 thr
// wave (wo in {0..3}, wsrow in {0,1}): 128 cout x row(hpair*2+wsrow) x 64 w
__global__ __launch_bounds__(512, 2) void k_conv(
    const short* __restrict__ xm, const short* __restrict__ wpk,
    const float* __restrict__ demod, const float* __restrict__ convb,
    const float* __restrict__ nscal, const float* __restrict__ noise,
    const float* __restrict__ t, const float* __restrict__ prelu_a,
    float* __restrict__ y) {
  __shared__ char WTs[3][32768];   // ring: [512 o][4 sp]x16B per tap slot
  __shared__ char XMs[2][16896];   // [4 r][66 wp][4 slot]x16B per buffer

  int tid = threadIdx.x;
  int bid = blockIdx.x;
  int hpair = bid & 31, b = bid >> 5;
  int wid = tid >> 6, lane = tid & 63;
  int wo = wid & 3, wsrow = wid >> 2;
  int l31 = lane & 31, lg = lane >> 5;

  const short* xb = xm + ((size_t)b * 66 + hpair * 2) * 66 * 512;
  int wb0 = ((wo * 128 + l31) << 6) + ((lg ^ ((l31 >> 1) & 3)) << 4);

  // per-thread xm staging units: u0=tid, u1=512+tid, u2=1024+(tid&31) (dup x16)
  int off0, off1, off2, d0, d1, d2;
  {
    int u = tid;
    int r = u / 264, rem = u - r * 264; int wp = rem >> 2, sp = rem & 3;
    off0 = (r * 66 + wp) * 512 + ((sp ^ ((wp >> 1) & 3)) << 3); d0 = u * 16;
    u = 512 + tid;
    r = u / 264; rem = u - r * 264; wp = rem >> 2; sp = rem & 3;
    off1 = (r * 66 + wp) * 512 + ((sp ^ ((wp >> 1) & 3)) << 3); d1 = u * 16;
    u = 1024 + (tid & 31);
    rem = u - 792;                  // r = 3
    wp = rem >> 2; sp = rem & 3;
    off2 = (3 * 66 + wp) * 512 + ((sp ^ ((wp >> 1) & 3)) << 3); d2 = u * 16;
  }

  // ---- prologue: XM(cc0) + WT taps 0,1 of cc0 ----
  gld16(xb + off0, XMs[0] + d0);
  gld16(xb + off1, XMs[0] + d1);
  gld16(xb + off2, XMs[0] + d2);      // duplicated writes, same data
  #pragma unroll
  for (int tt = 0; tt < 2; ++tt) {
    const short* ws = wpk + (size_t)(tt * 16) * 16384;
    #pragma unroll
    for (int j = 0; j < 4; ++j)
      gld16(ws + (j * 512 + tid) * 8, WTs[tt] + (j * 512 + tid) * 16);
  }

  f32x16 zf = {0,0,0,0,0,0,0,0,0,0,0,0,0,0,0,0};
  f32x16 acc[4][2];
  #pragma unroll
  for (int i = 0; i < 4; ++i) { acc[i][0] = zf; acc[i][1] = zf; }

  asm volatile("s_waitcnt vmcnt(0)" ::: "memory");
  __builtin_amdgcn_s_barrier();

  short8v xr0, xr1, xr2;

  #pragma unroll 1
  for (int cc = 0; cc < 16; ++cc) {
    const char* XMc = XMs[cc & 1];
    char* XMn = (char*)XMs[(cc & 1) ^ 1];
    #pragma unroll
    for (int tp = 0; tp < 9; ++tp) {
      const int kh = tp / 3, kw = tp % 3;

      // 1. stage WT for phase+2 (4 gld16, uniform) — skip last two phases
      if (!(cc == 15 && tp >= 7)) {
        const int ntap = (tp + 2) % 9;
        int ncc = cc + (tp >= 7 ? 1 : 0);
        const short* ws = wpk + (size_t)(ntap * 16 + ncc) * 16384;
        char* wd = (char*)WTs[(tp + 2) % 3];
        #pragma unroll
        for (int j = 0; j < 4; ++j)
          gld16(ws + (j * 512 + tid) * 8, wd + (j * 512 + tid) * 16);
      }
      // order fence: xm reg-loads must be NEWER than the WT batch above
      asm volatile("" ::: "memory");
      // 2. xm reg-loads for cc+1 (issued once per cc, after WT batch)
      if (tp == 0 && cc < 15) {
        const short* xs = xb + (cc + 1) * 32;
        xr0 = *(const short8v*)(xs + off0);
        xr1 = *(const short8v*)(xs + off1);
        xr2 = *(const short8v*)(xs + off2);
      }
      // 3. ds_write xm for cc+1 (loads aged 7 phases; compiler waits them)
      if (tp == 7 && cc < 15) {
        *(short8v*)(XMn + d0) = xr0;
        *(short8v*)(XMn + d1) = xr1;
        if (tid < 32) *(short8v*)(XMn + d2) = xr2;
      }

      // 4. ds_read operands for this tap (12 x b128, both swizzled)
      const char* Wp = (const char*)WTs[tp % 3];
      bf16x8 wf0[4], wf1[4];
      #pragma unroll
      for (int cf = 0; cf < 4; ++cf) {
        wf0[cf] = *(const bf16x8*)(Wp + (wb0 + cf * 2048));
        wf1[cf] = *(const bf16x8*)(Wp + ((wb0 + cf * 2048) ^ 32));
      }
      int a = l31 + kw;
      int xo = ((wsrow + kh) * 66 + a) * 64 + ((lg ^ ((a >> 1) & 3)) << 4);
      bf16x8 xf00 = *(const bf16x8*)(XMc + xo);
      bf16x8 xf01 = *(const bf16x8*)(XMc + xo + 2048);
      bf16x8 xf10 = *(const bf16x8*)(XMc + (xo ^ 32));
      bf16x8 xf11 = *(const bf16x8*)(XMc + ((xo ^ 32) + 2048));

      __builtin_amdgcn_s_barrier();                 // bar1
      __builtin_amdgcn_s_setprio(1);
      acc[0][0] = __builtin_amdgcn_mfma_f32_32x32x16_bf16(wf0[0], xf00, acc[0][0], 0, 0, 0);
      acc[0][1] = __builtin_amdgcn_mfma_f32_32x32x16_bf16(wf0[0], xf01, acc[0][1], 0, 0, 0);
      acc[1][0] = __builtin_amdgcn_mfma_f32_32x32x16_bf16(wf0[1], xf00, acc[1][0], 0, 0, 0);
      acc[1][1] = __builtin_amdgcn_mfma_f32_32x32x16_bf16(wf0[1], xf01, acc[1][1], 0, 0, 0);
      acc[2][0] = __builtin_amdgcn_mfma_f32_32x32x16_bf16(wf0[2], xf00, acc[2][0], 0, 0, 0);
      acc[2][1] = __builtin_amdgcn_mfma_f32_32x32x16_bf16(wf0[2], xf01, acc[2][1], 0, 0, 0);
      acc[3][0] = __builtin_amdgcn_mfma_f32_32x32x16_bf16(wf0[3], xf00, acc[3][0], 0, 0, 0);
      acc[3][1] = __builtin_amdgcn_mfma_f32_32x32x16_bf16(wf0[3], xf01, acc[3][1], 0, 0, 0);
      acc[0][0] = __builtin_amdgcn_mfma_f32_32x32x16_bf16(wf1[0], xf10, acc[0][0], 0, 0, 0);
      acc[0][1] = __builtin_amdgcn_mfma_f32_32x32x16_bf16(wf1[0], xf11, acc[0][1], 0, 0, 0);
      acc[1][0] = __builtin_amdgcn_mfma_f32_32x32x16_bf16(wf1[1], xf10, acc[1][0], 0, 0, 0);
      acc[1][1] = __builtin_amdgcn_mfma_f32_32x32x16_bf16(wf1[1], xf11, acc[1][1], 0, 0, 0);
      acc[2][0] = __builtin_amdgcn_mfma_f32_32x32x16_bf16(wf1[2], xf10, acc[2][0], 0, 0, 0);
      acc[2][1] = __builtin_amdgcn_mfma_f32_32x32x16_bf16(wf1[2], xf11, acc[2][1], 0, 0, 0);
      acc[3][0] = __builtin_amdgcn_mfma_f32_32x32x16_bf16(wf1[3], xf10, acc[3][0], 0, 0, 0);
      acc[3][1] = __builtin_amdgcn_mfma_f32_32x32x16_bf16(wf1[3], xf11, acc[3][1], 0, 0, 0);
      __builtin_amdgcn_s_setprio(0);

      // 5. counted end-of-phase wait (never 0 mid-loop), then bar2
      if (cc < 15) {
        if (tp <= 1)      asm volatile("s_waitcnt vmcnt(7)" ::: "memory");
        else if (tp == 8) asm volatile("s_waitcnt vmcnt(4) lgkmcnt(0)" ::: "memory");
        else              asm volatile("s_waitcnt vmcnt(4)" ::: "memory");
      } else {
        if (tp <= 6)      asm volatile("s_waitcnt vmcnt(4)" ::: "memory");
        else              asm volatile("s_waitcnt vmcnt(0) lgkmcnt(0)" ::: "memory");
      }
      __builtin_amdgcn_s_barrier();                 // bar2
    }
  }

  // ---- epilogue: demod + bias + noise + prelu + (y+t)/sqrt2 ----
  float pa = prelu_a[0];
  const float inv_r2 = 1.0f / 1.41421f;
  int h = hpair * 2 + wsrow;
  float nz0 = noise[((size_t)b * 64 + h) * 64 + l31];
  float nz1 = noise[((size_t)b * 64 + h) * 64 + 32 + l31];
  #pragma unroll
  for (int cf = 0; cf < 4; ++cf) {
    #pragma unroll
    for (int reg = 0; reg < 16; ++reg) {
      int orow = (reg & 3) + 8 * (reg >> 2) + 4 * lg;
      int o = wo * 128 + cf * 32 + orow;
      float dm = demod[b * 512 + o];
      float cb = convb[o];
      float ns = nscal[o];
      #pragma unroll
      for (int sf = 0; sf < 2; ++sf) {
        int w = sf * 32 + l31;
        float v = acc[cf][sf][reg];
        v = v * dm + cb + ns * (sf ? nz1 : nz0);
        v = (v >= 0.f) ? v : pa * v;
        size_t oi = (((size_t)b * 512 + o) * 64 + h) * 64 + w;
        v = (v + t[oi]) * inv_r2;
        y[oi] = v;
      }
    }
  }
}

// ---------------- toRGB: 1x1 conv over 512 ch + clamp -----------------------
__global__ void k_rgb(const float* __restrict__ y, const float* __restrict__ ow,
                      const float* __restrict__ ob, float* __restrict__ out) {
  int b = blockIdx.x >> 6, h = blockIdx.x & 63;
  int w = threadIdx.x & 63, g = threadIdx.x >> 6;
  const float* yb = y + (((size_t)b * 512) * 64 + h) * 64 + w;
  float s0 = 0.f, s1 = 0.f, s2 = 0.f;
  for (int o = g * 128; o < g * 128 + 128; ++o) {
    float v = yb[(size_t)o * 4096];
    s0 += v * ow[o];
    s1 += v * ow[512 + o];
    s2 += v * ow[1024 + o];
  }
  __shared__ float red[3][4][64];
  red[0][g][w] = s0; red[1][g][w] = s1; red[2][g][w] = s2;
  __syncthreads();
  if (threadIdx.x < 192) {
    int c = threadIdx.x >> 6, ww = threadIdx.x & 63;
    float s = red[c][0][ww] + red[c][1][ww] + red[c][2][ww] + red[c][3][ww];
    s = s * 0.0625f + ob[c];
    s = fminf(fmaxf(s, 0.f), 1.f);
    out[(((size_t)b * 3 + c) * 64 + h) * 64 + ww] = s;
  }
}

extern "C" void kernel_launch(void* const* d_in, const int* in_sizes, int n_in,
                              void* d_out, int out_size, void* d_ws, size_t ws_size,
                              hipStream_t stream) {
  const float* x     = (const float*)d_in[0];
  const float* sb    = (const float*)d_in[1];
  const float* noise = (const float*)d_in[2];
  const float* t     = (const float*)d_in[3];
  const float* aw    = (const float*)d_in[4];
  const float* ab    = (const float*)d_in[5];
  const float* cw    = (const float*)d_in[6];
  const float* cb    = (const float*)d_in[7];
  const float* pa    = (const float*)d_in[8];
  const float* ns    = (const float*)d_in[9];
  const float* ow    = (const float*)d_in[10];
  const float* ob    = (const float*)d_in[11];
  char* ws = (char*)d_ws;
  float* style = (float*)(ws + WS_STYLE);
  float* demod = (float*)(ws + WS_DEMOD);
  float* wsq   = (float*)(ws + WS_WSQ);
  short* wpk   = (short*)(ws + WS_WPACK);
  short* xmw   = (short*)(ws + WS_XM);
  float* y   = (float*)d_out;
  float* out = y + 16777216;

  k_style<<<8, 256, 0, stream>>>(sb, aw, ab, style);
  k_wsq<<<1024, 256, 0, stream>>>(cw, wsq);
  k_demod<<<1024, 256, 0, stream>>>(wsq, style, demod);
  k_upsample<<<528, 256, 0, stream>>>(x, style, xmw);
  k_packw<<<1152, 256, 0, stream>>>(cw, wpk);
  k_conv<<<256, 512, 0, stream>>>(xmw, wpk, demod, cb, ns, noise, t, pa, y);
  k_rgb<<<512, 256, 0, stream>>>(y, ow, ob, out);
}